// Round 1
// baseline (10250.101 us; speedup 1.0000x reference)
//
#include <hip/hip_runtime.h>
#include <cstdint>
#include <cstddef>

typedef __bf16 bf16;
typedef __bf16 bf16x8 __attribute__((ext_vector_type(8)));
typedef float f32x4 __attribute__((ext_vector_type(4)));

#define MFMA16(a, b, c) __builtin_amdgcn_mfma_f32_16x16x32_bf16((a), (b), (c), 0, 0, 0)

__device__ __forceinline__ float fast_tanh(float x) {
  x = fminf(fmaxf(x, -15.f), 15.f);
  float e = __expf(2.f * x);
  return (e - 1.f) / (e + 1.f);
}
__device__ __forceinline__ float fast_sigmoid(float x) {
  return 1.f / (1.f + __expf(-x));
}

// ---------------- setup kernels ----------------

// float -> (hi, lo) bf16 split, elementwise
__global__ void cast_split_kernel(const float* __restrict__ src,
                                  bf16* __restrict__ hi, bf16* __restrict__ lo, int n) {
  int i = blockIdx.x * 256 + threadIdx.x;
  if (i < n) {
    float x = src[i];
    bf16 h = (bf16)x;
    hi[i] = h;
    lo[i] = (bf16)(x - (float)h);
  }
}

// dst[(c)*R + r] = cast(src[r*C + c]); dst shape (C, R). lo may be null.
__global__ void tc_kernel(const float* __restrict__ src, bf16* __restrict__ hi,
                          bf16* __restrict__ lo, int R, int C) {
  __shared__ float tile[32][33];
  int c0 = blockIdx.x * 32, r0 = blockIdx.y * 32;
  int tx = threadIdx.x & 31, ty = threadIdx.x >> 5;  // 256 threads: ty 0..7
  for (int i = ty; i < 32; i += 8)
    tile[i][tx] = src[(size_t)(r0 + i) * C + c0 + tx];
  __syncthreads();
  for (int i = ty; i < 32; i += 8) {
    float x = tile[tx][i];
    bf16 h = (bf16)x;
    size_t idx = (size_t)(c0 + i) * R + r0 + tx;
    hi[idx] = h;
    if (lo) lo[idx] = (bf16)(x - (float)h);
  }
}

// ---------------- GEMM bodies ----------------
// Block = 256 thr (4 waves). Block computes 64(M)x64(N). Wave w: rows [16w,16w+16).
// A (M x lda) row-major bf16; BT (N x ldb) row-major bf16 (= B transposed).
// MFMA 16x16x32 frag layout: A[m=lane&15][k=(lane>>4)*8+j]; BT same pattern;
// D: row=(lane>>4)*4+i, col=lane&15.

template <int ATOMIC>
__device__ __forceinline__ void gemm_body(const bf16* __restrict__ A, int lda,
                                          const bf16* __restrict__ BT, int ldb,
                                          float* __restrict__ C, int ldc,
                                          int mb, int nb, int k0, int kSteps) {
  int lane = threadIdx.x & 63, wave = threadIdx.x >> 6;
  int mrow = mb * 64 + wave * 16 + (lane & 15);
  int qk = (lane >> 4) * 8;
  const bf16* ap = A + (size_t)mrow * lda + k0 + qk;
  int ncol = nb * 64 + (lane & 15);
  const bf16* bp[4];
#pragma unroll
  for (int j = 0; j < 4; ++j) bp[j] = BT + (size_t)(ncol + 16 * j) * ldb + k0 + qk;
  f32x4 acc[4];
#pragma unroll
  for (int j = 0; j < 4; ++j) acc[j] = {0.f, 0.f, 0.f, 0.f};
  for (int s = 0; s < kSteps; ++s) {
    bf16x8 a = *(const bf16x8*)ap; ap += 32;
#pragma unroll
    for (int j = 0; j < 4; ++j) {
      bf16x8 b = *(const bf16x8*)bp[j]; bp[j] += 32;
      acc[j] = MFMA16(a, b, acc[j]);
    }
  }
  int row = mb * 64 + wave * 16 + (lane >> 4) * 4;
  int col = nb * 64 + (lane & 15);
#pragma unroll
  for (int j = 0; j < 4; ++j)
#pragma unroll
    for (int i = 0; i < 4; ++i) {
      size_t idx = (size_t)(row + i) * ldc + col + j * 16;
      if (ATOMIC) atomicAdd(&C[idx], acc[j][i]); else C[idx] = acc[j][i];
    }
}

// split-bf16 (hi+lo) version: acc += Ah*Bh + Ah*Bl + Al*Bh  (~fp32 accuracy)
__device__ __forceinline__ void gemm_split_body(const bf16* __restrict__ Ahi,
                                                const bf16* __restrict__ Alo, int lda,
                                                const bf16* __restrict__ Bhi,
                                                const bf16* __restrict__ Blo, int ldb,
                                                float* __restrict__ C, int ldc,
                                                int mb, int nb, int kSteps) {
  int lane = threadIdx.x & 63, wave = threadIdx.x >> 6;
  int mrow = mb * 64 + wave * 16 + (lane & 15);
  int qk = (lane >> 4) * 8;
  const bf16* ah = Ahi + (size_t)mrow * lda + qk;
  const bf16* al = Alo + (size_t)mrow * lda + qk;
  int ncol = nb * 64 + (lane & 15);
  const bf16* bh[4]; const bf16* bl[4];
#pragma unroll
  for (int j = 0; j < 4; ++j) {
    bh[j] = Bhi + (size_t)(ncol + 16 * j) * ldb + qk;
    bl[j] = Blo + (size_t)(ncol + 16 * j) * ldb + qk;
  }
  f32x4 acc[4];
#pragma unroll
  for (int j = 0; j < 4; ++j) acc[j] = {0.f, 0.f, 0.f, 0.f};
  for (int s = 0; s < kSteps; ++s) {
    bf16x8 Ah = *(const bf16x8*)ah; ah += 32;
    bf16x8 Al = *(const bf16x8*)al; al += 32;
#pragma unroll
    for (int j = 0; j < 4; ++j) {
      bf16x8 Bh = *(const bf16x8*)bh[j]; bh[j] += 32;
      bf16x8 Bl = *(const bf16x8*)bl[j]; bl[j] += 32;
      acc[j] = MFMA16(Ah, Bh, acc[j]);
      acc[j] = MFMA16(Ah, Bl, acc[j]);
      acc[j] = MFMA16(Al, Bh, acc[j]);
    }
  }
  int row = mb * 64 + wave * 16 + (lane >> 4) * 4;
  int col = nb * 64 + (lane & 15);
#pragma unroll
  for (int j = 0; j < 4; ++j)
#pragma unroll
    for (int i = 0; i < 4; ++i)
      C[(size_t)(row + i) * ldc + col + j * 16] = acc[j][i];
}

__global__ __launch_bounds__(256) void gemm_kernel(const bf16* __restrict__ A, int lda,
                                                   const bf16* __restrict__ BT, int ldb,
                                                   float* __restrict__ C, int ldc,
                                                   int nbN, int kSteps) {
  gemm_body<0>(A, lda, BT, ldb, C, ldc, blockIdx.x / nbN, blockIdx.x % nbN, 0, kSteps);
}

__global__ __launch_bounds__(256) void gemm_split_kernel(const bf16* __restrict__ Ahi,
                                                         const bf16* __restrict__ Alo, int lda,
                                                         const bf16* __restrict__ Bhi,
                                                         const bf16* __restrict__ Blo, int ldb,
                                                         float* __restrict__ C, int ldc,
                                                         int nbN, int kSteps) {
  gemm_split_body(Ahi, Alo, lda, Bhi, Blo, ldb, C, ldc, blockIdx.x / nbN, blockIdx.x % nbN, kSteps);
}

// ---------------- per-step kernels ----------------

// K1: blocks [0,64): attention for batch row b (fp32). blocks [64,264): t1 += y@Ey_t split-K.
__global__ __launch_bounds__(256) void k1_attn_t1(
    const float* __restrict__ Ws, const float* __restrict__ U_h,
    const float* __restrict__ attnb, const float* __restrict__ vvec,
    const float* __restrict__ inseq,
    bf16* __restrict__ ctx_hi, bf16* __restrict__ ctx_lo,
    const bf16* __restrict__ y_bf, const bf16* __restrict__ EyT,
    float* __restrict__ t1f) {
  int bx = blockIdx.x;
  if (bx < 64) {
    __shared__ float sWs[512];
    __shared__ float sV[512];
    __shared__ float sE[64];
    __shared__ float sAl[64];
    int t = threadIdx.x;
    for (int c = t; c < 512; c += 256) {
      sWs[c] = Ws[bx * 512 + c] + attnb[c];
      sV[c] = vvec[c];
    }
    __syncthreads();
    // e[j] = sum_c v[c] * tanh(Ws[c] + U_h[b,j,c] + b[c])
    int j = t >> 2, q = t & 3;
    const float* uh = U_h + ((size_t)(bx * 64 + j)) * 512 + q * 128;
    float part = 0.f;
#pragma unroll 4
    for (int c = 0; c < 128; ++c) {
      int cc = q * 128 + c;
      part += sV[cc] * fast_tanh(sWs[cc] + uh[c]);
    }
    part += __shfl_xor(part, 1);
    part += __shfl_xor(part, 2);
    if (q == 0) sE[j] = part;
    __syncthreads();
    if (t < 64) {
      float x = sE[t];
      float m = x;
      for (int off = 32; off; off >>= 1) m = fmaxf(m, __shfl_xor(m, off));
      float a = __expf(x - m);
      float ssum = a;
      for (int off = 32; off; off >>= 1) ssum += __shfl_xor(ssum, off);
      sAl[t] = a / ssum;
    }
    __syncthreads();
    // ctx[c] = sum_j alpha[j] * input_seq[b,j,c]
    for (int c = t; c < 512; c += 256) {
      float acc = 0.f;
      const float* ip = inseq + ((size_t)bx * 64) * 512 + c;
#pragma unroll 8
      for (int jj = 0; jj < 64; ++jj) acc += sAl[jj] * ip[(size_t)jj * 512];
      bf16 h = (bf16)acc;
      ctx_hi[bx * 512 + c] = h;
      ctx_lo[bx * 512 + c] = (bf16)(acc - (float)h);
    }
  } else {
    // t1 (64x512) += y_bf(64x32000) @ Ey_t : 8 n-blocks x 25 k-splits, 40 ksteps each
    int b2 = bx - 64;
    int nb = b2 & 7;
    int kb = b2 >> 3;
    gemm_body<1>(y_bf, 32000, EyT, 32000, t1f, 512, 0, nb, kb * 1280, 40);
  }
}

// K2: fused GRU cell. 64 blocks, each owns h-chunk of 16. split-bf16 MFMA for gi, gh.
__global__ __launch_bounds__(256) void k2_gru(
    const bf16* __restrict__ ctx_hi, const bf16* __restrict__ ctx_lo,
    const bf16* __restrict__ s_hi, const bf16* __restrict__ s_lo,
    const bf16* __restrict__ Wih_hi, const bf16* __restrict__ Wih_lo,
    const bf16* __restrict__ Whh_hi, const bf16* __restrict__ Whh_lo,
    const float* __restrict__ b_ih, const float* __restrict__ b_hh,
    const float* __restrict__ s_cur, float* __restrict__ s_next,
    bf16* __restrict__ sn_hi, bf16* __restrict__ sn_lo) {
  int h0 = blockIdx.x * 16;
  int lane = threadIdx.x & 63, wave = threadIdx.x >> 6;
  int m = wave * 16 + (lane & 15);
  int qk = (lane >> 4) * 8;
  int hl = lane & 15;
  f32x4 gi[3], gh[3];
#pragma unroll
  for (int g = 0; g < 3; ++g) { gi[g] = {0.f, 0.f, 0.f, 0.f}; gh[g] = {0.f, 0.f, 0.f, 0.f}; }
  {  // gi = ctx @ W_ih^T  (K=512)
    const bf16* ah = ctx_hi + (size_t)m * 512 + qk;
    const bf16* al = ctx_lo + (size_t)m * 512 + qk;
    const bf16* bh[3]; const bf16* bl[3];
#pragma unroll
    for (int g = 0; g < 3; ++g) {
      size_t r = (size_t)(g * 1024 + h0 + hl) * 512 + qk;
      bh[g] = Wih_hi + r; bl[g] = Wih_lo + r;
    }
    for (int s = 0; s < 16; ++s) {
      bf16x8 Ah = *(const bf16x8*)ah; ah += 32;
      bf16x8 Al = *(const bf16x8*)al; al += 32;
#pragma unroll
      for (int g = 0; g < 3; ++g) {
        bf16x8 Bh = *(const bf16x8*)bh[g]; bh[g] += 32;
        bf16x8 Bl = *(const bf16x8*)bl[g]; bl[g] += 32;
        gi[g] = MFMA16(Ah, Bh, gi[g]);
        gi[g] = MFMA16(Ah, Bl, gi[g]);
        gi[g] = MFMA16(Al, Bh, gi[g]);
      }
    }
  }
  {  // gh = s @ W_hh^T  (K=1024)
    const bf16* ah = s_hi + (size_t)m * 1024 + qk;
    const bf16* al = s_lo + (size_t)m * 1024 + qk;
    const bf16* bh[3]; const bf16* bl[3];
#pragma unroll
    for (int g = 0; g < 3; ++g) {
      size_t r = (size_t)(g * 1024 + h0 + hl) * 1024 + qk;
      bh[g] = Whh_hi + r; bl[g] = Whh_lo + r;
    }
    for (int s = 0; s < 32; ++s) {
      bf16x8 Ah = *(const bf16x8*)ah; ah += 32;
      bf16x8 Al = *(const bf16x8*)al; al += 32;
#pragma unroll
      for (int g = 0; g < 3; ++g) {
        bf16x8 Bh = *(const bf16x8*)bh[g]; bh[g] += 32;
        bf16x8 Bl = *(const bf16x8*)bl[g]; bl[g] += 32;
        gh[g] = MFMA16(Ah, Bh, gh[g]);
        gh[g] = MFMA16(Ah, Bl, gh[g]);
        gh[g] = MFMA16(Al, Bh, gh[g]);
      }
    }
  }
  int hg = h0 + hl;
  float bir = b_ih[hg], biz = b_ih[1024 + hg], bin = b_ih[2048 + hg];
  float bhr = b_hh[hg], bhz = b_hh[1024 + hg], bhn = b_hh[2048 + hg];
  int brow0 = wave * 16 + (lane >> 4) * 4;
#pragma unroll
  for (int i = 0; i < 4; ++i) {
    int b = brow0 + i;
    float r = fast_sigmoid(gi[0][i] + bir + gh[0][i] + bhr);
    float z = fast_sigmoid(gi[1][i] + biz + gh[1][i] + bhz);
    float n = fast_tanh(gi[2][i] + bin + r * (gh[2][i] + bhn));
    float so = s_cur[(size_t)b * 1024 + hg];
    float sn = (1.f - z) * n + z * so;
    s_next[(size_t)b * 1024 + hg] = sn;
    bf16 hh = (bf16)sn;
    sn_hi[(size_t)b * 1024 + hg] = hh;
    sn_lo[(size_t)b * 1024 + hg] = (bf16)(sn - (float)hh);
  }
}

// K3: blocks [0,64): t = s_new@U_o + t1@V_o + ctx@C_o, maxout -> tm_bf (h-chunk 16/block).
//     blocks [64,72): Ws = s_new @ W (for next step's attention).
__global__ __launch_bounds__(256) void k3_deepout(
    const bf16* __restrict__ sn_hi, const bf16* __restrict__ sn_lo,
    const float* __restrict__ t1f,
    const bf16* __restrict__ ctx_hi, const bf16* __restrict__ ctx_lo,
    const bf16* __restrict__ UoT_hi, const bf16* __restrict__ UoT_lo,
    const bf16* __restrict__ VoT_hi, const bf16* __restrict__ VoT_lo,
    const bf16* __restrict__ CoT_hi, const bf16* __restrict__ CoT_lo,
    const bf16* __restrict__ WT_hi, const bf16* __restrict__ WT_lo,
    bf16* __restrict__ tm_bf, float* __restrict__ Ws_out) {
  int bx = blockIdx.x;
  int lane = threadIdx.x & 63, wave = threadIdx.x >> 6;
  int qk = (lane >> 4) * 8;
  if (bx < 64) {
    int n0 = bx * 16;
    int m = wave * 16 + (lane & 15);
    int nr = n0 + (lane & 15);
    f32x4 acc = {0.f, 0.f, 0.f, 0.f};
    {  // s_new @ U_o (K=1024), split
      const bf16* ah = sn_hi + (size_t)m * 1024 + qk;
      const bf16* al = sn_lo + (size_t)m * 1024 + qk;
      const bf16* bh = UoT_hi + (size_t)nr * 1024 + qk;
      const bf16* bl = UoT_lo + (size_t)nr * 1024 + qk;
      for (int s = 0; s < 32; ++s) {
        bf16x8 Ah = *(const bf16x8*)ah; ah += 32;
        bf16x8 Al = *(const bf16x8*)al; al += 32;
        bf16x8 Bh = *(const bf16x8*)bh; bh += 32;
        bf16x8 Bl = *(const bf16x8*)bl; bl += 32;
        acc = MFMA16(Ah, Bh, acc); acc = MFMA16(Ah, Bl, acc); acc = MFMA16(Al, Bh, acc);
      }
    }
    {  // t1 @ V_o (K=512), t1 fp32 split on the fly
      const float* ap = t1f + (size_t)m * 512 + qk;
      const bf16* bh = VoT_hi + (size_t)nr * 512 + qk;
      const bf16* bl = VoT_lo + (size_t)nr * 512 + qk;
      for (int s = 0; s < 16; ++s) {
        f32x4 f0 = *(const f32x4*)ap;
        f32x4 f1 = *(const f32x4*)(ap + 4);
        ap += 32;
        bf16x8 Ah, Al;
#pragma unroll
        for (int i = 0; i < 4; ++i) {
          bf16 h = (bf16)f0[i]; Ah[i] = h; Al[i] = (bf16)(f0[i] - (float)h);
          h = (bf16)f1[i]; Ah[4 + i] = h; Al[4 + i] = (bf16)(f1[i] - (float)h);
        }
        bf16x8 Bh = *(const bf16x8*)bh; bh += 32;
        bf16x8 Bl = *(const bf16x8*)bl; bl += 32;
        acc = MFMA16(Ah, Bh, acc); acc = MFMA16(Ah, Bl, acc); acc = MFMA16(Al, Bh, acc);
      }
    }
    {  // ctx @ C_o (K=512), split
      const bf16* ah = ctx_hi + (size_t)m * 512 + qk;
      const bf16* al = ctx_lo + (size_t)m * 512 + qk;
      const bf16* bh = CoT_hi + (size_t)nr * 512 + qk;
      const bf16* bl = CoT_lo + (size_t)nr * 512 + qk;
      for (int s = 0; s < 16; ++s) {
        bf16x8 Ah = *(const bf16x8*)ah; ah += 32;
        bf16x8 Al = *(const bf16x8*)al; al += 32;
        bf16x8 Bh = *(const bf16x8*)bh; bh += 32;
        bf16x8 Bl = *(const bf16x8*)bl; bl += 32;
        acc = MFMA16(Ah, Bh, acc); acc = MFMA16(Ah, Bl, acc); acc = MFMA16(Al, Bh, acc);
      }
    }
    // maxout over adjacent col pairs (cols n0+c, c=lane&15; pair via lane^1)
    int col = lane & 15;
    int row0 = wave * 16 + (lane >> 4) * 4;
#pragma unroll
    for (int i = 0; i < 4; ++i) {
      float vme = acc[i];
      float vot = __shfl_xor(vme, 1);
      float mx = fmaxf(vme, vot);
      if (!(col & 1)) {
        int d = (n0 + col) >> 1;
        tm_bf[(size_t)(row0 + i) * 512 + d] = (bf16)mx;
      }
    }
  } else {
    // Ws = s_new @ W : N=512 (8 n-blocks), K=1024, split
    gemm_split_body(sn_hi, sn_lo, 1024, WT_hi, WT_lo, 1024, Ws_out, 512, 0, bx - 64, 32);
  }
}

// K5: softmax over vocab per batch row; write out slice + y_bf; zero t1f for next step.
__global__ __launch_bounds__(1024) void k5_softmax(
    const float* __restrict__ logits, float* __restrict__ out,
    bf16* __restrict__ y_bf, float* __restrict__ t1f, int step) {
  int b = blockIdx.x, t = threadIdx.x;
  const float* lr = logits + (size_t)b * 32000;
  float x[32];
  float mx = -1e30f;
#pragma unroll
  for (int i = 0; i < 32; ++i) {
    int k = i * 1024 + t;
    if (k < 32000) { float v = lr[k]; x[i] = v; mx = fmaxf(mx, v); }
  }
  __shared__ float red[16];
  int lane = t & 63, wv = t >> 6;
  for (int off = 32; off; off >>= 1) mx = fmaxf(mx, __shfl_xor(mx, off));
  if (lane == 0) red[wv] = mx;
  __syncthreads();
  if (wv == 0) {
    float m2 = (lane < 16) ? red[lane] : -1e30f;
    for (int off = 8; off; off >>= 1) m2 = fmaxf(m2, __shfl_xor(m2, off));
    if (lane == 0) red[0] = m2;
  }
  __syncthreads();
  mx = red[0];
  __syncthreads();
  float sum = 0.f;
#pragma unroll
  for (int i = 0; i < 32; ++i) {
    int k = i * 1024 + t;
    if (k < 32000) { float e = __expf(x[i] - mx); x[i] = e; sum += e; }
  }
  for (int off = 32; off; off >>= 1) sum += __shfl_xor(sum, off);
  if (lane == 0) red[wv] = sum;
  __syncthreads();
  if (wv == 0) {
    float s2 = (lane < 16) ? red[lane] : 0.f;
    for (int off = 8; off; off >>= 1) s2 += __shfl_xor(s2, off);
    if (lane == 0) red[0] = s2;
  }
  __syncthreads();
  float inv = 1.f / red[0];
  float* orow = out + ((size_t)step * 64 + b) * 32000;
  bf16* yrow = y_bf + (size_t)b * 32000;
#pragma unroll
  for (int i = 0; i < 32; ++i) {
    int k = i * 1024 + t;
    if (k < 32000) {
      float p = x[i] * inv;
      orow[k] = p;
      yrow[k] = (bf16)p;
    }
  }
  if (t < 512) t1f[(size_t)b * 512 + t] = 0.f;
}

// ---------------- host ----------------

extern "C" void kernel_launch(void* const* d_in, const int* in_sizes, int n_in,
                              void* d_out, int out_size, void* d_ws, size_t ws_size,
                              hipStream_t stream) {
  const float* input_seq = (const float*)d_in[0];
  const float* Ey_t = (const float*)d_in[1];
  const float* W = (const float*)d_in[2];
  const float* U = (const float*)d_in[3];
  const float* attnb = (const float*)d_in[4];
  const float* vvec = (const float*)d_in[5];
  const float* W_ih = (const float*)d_in[6];
  const float* W_hh = (const float*)d_in[7];
  const float* b_ih = (const float*)d_in[8];
  const float* b_hh = (const float*)d_in[9];
  const float* U_o = (const float*)d_in[10];
  const float* V_o = (const float*)d_in[11];
  const float* C_o = (const float*)d_in[12];
  const float* W_o = (const float*)d_in[13];
  float* out = (float*)d_out;

  char* p = (char*)d_ws;
  auto alloc = [&](size_t bytes) -> char* {
    char* r = p;
    p += (bytes + 255) & ~(size_t)255;
    return r;
  };
  // --- zero block (memset once per launch) ---
  float* sbuf0 = (float*)alloc(64 * 1024 * 4);
  bf16* shi0 = (bf16*)alloc(64 * 1024 * 2);
  bf16* slo0 = (bf16*)alloc(64 * 1024 * 2);
  float* Ws = (float*)alloc(64 * 512 * 4);
  float* t1f = (float*)alloc(64 * 512 * 4);
  bf16* y_bf = (bf16*)alloc((size_t)64 * 32000 * 2);
  size_t zeroBytes = (size_t)(p - (char*)d_ws);
  // --- rest ---
  float* sbuf1 = (float*)alloc(64 * 1024 * 4);
  bf16* shi1 = (bf16*)alloc(64 * 1024 * 2);
  bf16* slo1 = (bf16*)alloc(64 * 1024 * 2);
  bf16* ctx_hi = (bf16*)alloc(64 * 512 * 2);
  bf16* ctx_lo = (bf16*)alloc(64 * 512 * 2);
  bf16* tm_bf = (bf16*)alloc(64 * 512 * 2);
  float* logits = (float*)alloc((size_t)64 * 32000 * 4);
  float* U_h = (float*)alloc((size_t)4096 * 512 * 4);
  bf16* in_hi = (bf16*)alloc((size_t)4096 * 512 * 2);
  bf16* in_lo = (bf16*)alloc((size_t)4096 * 512 * 2);
  bf16* UT_hi = (bf16*)alloc(512 * 512 * 2);
  bf16* UT_lo = (bf16*)alloc(512 * 512 * 2);
  bf16* EyT = (bf16*)alloc((size_t)512 * 32000 * 2);
  bf16* WoT = (bf16*)alloc((size_t)32000 * 512 * 2);
  bf16* UoT_hi = (bf16*)alloc((size_t)1024 * 1024 * 2);
  bf16* UoT_lo = (bf16*)alloc((size_t)1024 * 1024 * 2);
  bf16* VoT_hi = (bf16*)alloc((size_t)1024 * 512 * 2);
  bf16* VoT_lo = (bf16*)alloc((size_t)1024 * 512 * 2);
  bf16* CoT_hi = (bf16*)alloc((size_t)1024 * 512 * 2);
  bf16* CoT_lo = (bf16*)alloc((size_t)1024 * 512 * 2);
  bf16* WT_hi = (bf16*)alloc((size_t)512 * 1024 * 2);
  bf16* WT_lo = (bf16*)alloc((size_t)512 * 1024 * 2);
  bf16* Wih_hi = (bf16*)alloc((size_t)3072 * 512 * 2);
  bf16* Wih_lo = (bf16*)alloc((size_t)3072 * 512 * 2);
  bf16* Whh_hi = (bf16*)alloc((size_t)3072 * 1024 * 2);
  bf16* Whh_lo = (bf16*)alloc((size_t)3072 * 1024 * 2);

  hipMemsetAsync(d_ws, 0, zeroBytes, stream);

  // setup: casts / transposes / U_h
  cast_split_kernel<<<(4096 * 512) / 256, 256, 0, stream>>>(input_seq, in_hi, in_lo, 4096 * 512);
  cast_split_kernel<<<(3072 * 512) / 256, 256, 0, stream>>>(W_ih, Wih_hi, Wih_lo, 3072 * 512);
  cast_split_kernel<<<(3072 * 1024) / 256, 256, 0, stream>>>(W_hh, Whh_hi, Whh_lo, 3072 * 1024);
  tc_kernel<<<dim3(512 / 32, 512 / 32), 256, 0, stream>>>(U, UT_hi, UT_lo, 512, 512);
  tc_kernel<<<dim3(512 / 32, 32000 / 32), 256, 0, stream>>>(Ey_t, EyT, nullptr, 32000, 512);
  tc_kernel<<<dim3(32000 / 32, 512 / 32), 256, 0, stream>>>(W_o, WoT, nullptr, 512, 32000);
  tc_kernel<<<dim3(1024 / 32, 1024 / 32), 256, 0, stream>>>(U_o, UoT_hi, UoT_lo, 1024, 1024);
  tc_kernel<<<dim3(1024 / 32, 512 / 32), 256, 0, stream>>>(V_o, VoT_hi, VoT_lo, 512, 1024);
  tc_kernel<<<dim3(1024 / 32, 512 / 32), 256, 0, stream>>>(C_o, CoT_hi, CoT_lo, 512, 1024);
  tc_kernel<<<dim3(512 / 32, 1024 / 32), 256, 0, stream>>>(W, WT_hi, WT_lo, 1024, 512);
  // U_h = input_seq @ U : (4096 x 512), K=512, split
  gemm_split_kernel<<<64 * 8, 256, 0, stream>>>(in_hi, in_lo, 512, UT_hi, UT_lo, 512,
                                                U_h, 512, 8, 16);

  float* sb[2] = {sbuf0, sbuf1};
  bf16* sh[2] = {shi0, shi1};
  bf16* sl[2] = {slo0, slo1};

  for (int t = 0; t < 64; ++t) {
    int cur = t & 1;
    k1_attn_t1<<<264, 256, 0, stream>>>(Ws, U_h, attnb, vvec, input_seq,
                                        ctx_hi, ctx_lo, y_bf, EyT, t1f);
    k2_gru<<<64, 256, 0, stream>>>(ctx_hi, ctx_lo, sh[cur], sl[cur],
                                   Wih_hi, Wih_lo, Whh_hi, Whh_lo, b_ih, b_hh,
                                   sb[cur], sb[cur ^ 1], sh[cur ^ 1], sl[cur ^ 1]);
    k3_deepout<<<72, 256, 0, stream>>>(sh[cur ^ 1], sl[cur ^ 1], t1f, ctx_hi, ctx_lo,
                                       UoT_hi, UoT_lo, VoT_hi, VoT_lo, CoT_hi, CoT_lo,
                                       WT_hi, WT_lo, tm_bf, Ws);
    gemm_kernel<<<500, 256, 0, stream>>>(tm_bf, 512, WoT, 512, logits, 32000, 500, 16);
    k5_softmax<<<64, 1024, 0, stream>>>(logits, out, y_bf, t1f, t);
  }
  (void)in_sizes; (void)n_in; (void)out_size; (void)ws_size;
}